// Round 3
// baseline (409.658 us; speedup 1.0000x reference)
//
#include <hip/hip_runtime.h>

typedef __attribute__((ext_vector_type(8))) short short8;
typedef __attribute__((ext_vector_type(4))) float f32x4;

#define NN 8192
#define DD 64

// f32 -> bf16 RNE (used only for the internal y staging)
__device__ inline unsigned short f2bf(float f){
  unsigned b = __float_as_uint(f);
  b = (b + 0x7fffu + ((b >> 16) & 1u)) >> 16;
  return (unsigned short)b;
}

// ---------------------------------------------------------------------------
// Dtype evidence (rounds 0-2):
//  - R1 read inputs as bf16 -> NaN. Only f32-words-read-as-bf16 can NaN
//    (valid bf16 inputs are bounded; kernel has no other NaN path).
//    => feature/weight inputs are FLOAT32 => no bf16 conversion was applied
//    => reference output dtype stands: FLOAT32.
//  - R2 wrote bf16 output -> absmax 113.25 > max|ref|=89: exactly the
//    signature of packed bf16 pairs read back as f32 (first half ~|out|-sized
//    values at wrong slots, second half zeros). Math core audited clean.
//  => THIS ROUND: identical compute, output written as f32.
//
// Algebra: softmax rows sum to 1 exactly, so attn_agg == aggregated;
// Wa_w/Wa_b are provably unused.
//   out = x@(Wobj+Wskip) + r@Wrel + A^T @ (x@Wnobj + bnobj) + (bobj+brel+bskip)
// A entries are exactly 0.0/1.0 -> f32->bf16 truncation is EXACT -> bf16 MFMA
// for the big A^T y product; only y carries bf16 quantization (~0.04 absmax
// through 410-term sums, threshold is 1.78).
// ---------------------------------------------------------------------------

// Kernel 1: per-row projections.
//   accT[d][i] = x@(Wobj+Wskip) + r@Wrel + (bobj+brel+bskip)   (f32 [64][8192])
//   yT[d][i]   = bf16( x@Wnobj + bnobj )                       (bf16 [64][8192])
__global__ __launch_bounds__(256) void k_proj(
    const float* __restrict__ x, const float* __restrict__ r,
    const float* __restrict__ Wobj,  const float* __restrict__ bobj,
    const float* __restrict__ Wnobj, const float* __restrict__ bnobj,
    const float* __restrict__ Wrel,  const float* __restrict__ brel,
    const float* __restrict__ Wskip, const float* __restrict__ bskip,
    float* __restrict__ accT, unsigned short* __restrict__ yT)
{
  const int i  = blockIdx.x * 256 + threadIdx.x;   // row
  const int d0 = blockIdx.y * 8;                   // this block's 8 output dims

  float xv[DD], rv[DD];
  const float4* xp = (const float4*)(x + i * DD);
  const float4* rp = (const float4*)(r + i * DD);
#pragma unroll
  for (int p = 0; p < 16; p++){
    float4 u = xp[p];
    xv[4*p+0]=u.x; xv[4*p+1]=u.y; xv[4*p+2]=u.z; xv[4*p+3]=u.w;
    float4 v = rp[p];
    rv[4*p+0]=v.x; rv[4*p+1]=v.y; rv[4*p+2]=v.z; rv[4*p+3]=v.w;
  }

  float ay[8], az[8];
#pragma unroll
  for (int t = 0; t < 8; t++){ ay[t] = 0.f; az[t] = 0.f; }

  // weights are wave-uniform -> compiler emits s_loads; full unroll keeps
  // xv/rv register-indexed
#pragma unroll
  for (int k = 0; k < DD; k++){
    const float xk = xv[k], rk = rv[k];
    const int wb = k * DD + d0;
#pragma unroll
    for (int t = 0; t < 8; t++){
      ay[t] += xk * Wnobj[wb + t];
      az[t] += xk * Wobj [wb + t];
      az[t] += xk * Wskip[wb + t];
      az[t] += rk * Wrel [wb + t];
    }
  }

#pragma unroll
  for (int t = 0; t < 8; t++){
    ay[t] += bnobj[d0 + t];
    az[t] += bobj[d0 + t] + brel[d0 + t] + bskip[d0 + t];
    yT[(d0 + t) * NN + i]   = f2bf(ay[t]);   // coalesced: lanes = consecutive i
    accT[(d0 + t) * NN + i] = az[t];
  }
}

// ---------------------------------------------------------------------------
// Kernel 2: accT[d][j] += sum_k yT[d][k] * A[k][j]   (MFMA 16x16x32 bf16)
// M=64 (d), N=8192 (j), K=8192. Split-K=16 with fp32 atomics into accT.
// A (f32 0/1) is truncated to bf16 during LDS staging (exact).
// XOR-chunk swizzle keeps the k-strided B-frag ds_read_u16s 2-way (free).
// ---------------------------------------------------------------------------
#define BN 128
#define KSPLIT 16
#define KCH (NN / KSPLIT)   // 512
#define NIT (KCH / 64)      // 8

__global__ __launch_bounds__(256) void k_spmm(
    const float* __restrict__ A,
    const unsigned short* __restrict__ yT,
    float* __restrict__ accT)
{
  __shared__ short Alds[64 * 128];   // [k][j swizzled], row pitch 128 elems (256B)
  __shared__ short Ylds[64 * 72];    // [d][k], pitch 72 (conflict-free b128)

  const int tid  = threadIdx.x;
  const int lane = tid & 63;
  const int wave = tid >> 6;
  const int q    = lane >> 4;    // k-quad within fragment
  const int nn   = lane & 15;    // m (A-frag) / n (B-frag, C col) index

  const int j0     = blockIdx.x * BN;
  const int kstart = blockIdx.y * KCH;

  // A staging coords: 4 f32 columns (16B) per load
  const int c4 = tid & 31;       // 4-col chunk within 128-col row
  const int kr = tid >> 5;       // rows kr + p*8, p = 0..7
  // y staging coords
  const int cY = tid & 7;        // 16B chunk within 128B y row
  const int m0 = tid >> 3;       // y rows m0 + {0,32}

  uint4 abuf[8], ybuf[2];
  auto gload = [&](int it){
    const int kbase = kstart + it * 64;
#pragma unroll
    for (int p = 0; p < 8; p++)
      abuf[p] = *(const uint4*)(A + (size_t)(kbase + kr + p*8) * NN + j0 + c4 * 4);
#pragma unroll
    for (int p = 0; p < 2; p++)
      ybuf[p] = *(const uint4*)(yT + (m0 + p*32) * NN + kbase + cY * 8);
  };

  f32x4 acc[4][2];
#pragma unroll
  for (int a = 0; a < 4; a++)
#pragma unroll
    for (int b = 0; b < 2; b++)
      acc[a][b] = (f32x4){0.f, 0.f, 0.f, 0.f};

  gload(0);
  for (int it = 0; it < NIT; ++it){
    __syncthreads();               // previous compute done; LDS reusable
#pragma unroll
    for (int p = 0; p < 8; p++){
      const int kk  = kr + p*8;
      const int key = 2 * (p & 3);                 // == 2*((kk>>3)&3), kr<8
      // exact f32->bf16 truncation (A is 0/1), packed 2 at a time
      unsigned lo = (abuf[p].y & 0xFFFF0000u) | (abuf[p].x >> 16);
      unsigned hi = (abuf[p].w & 0xFFFF0000u) | (abuf[p].z >> 16);
      const int off = kk * 128 + (((c4 >> 1) ^ key) * 8) + (c4 & 1) * 4;
      *(uint2*)(&Alds[off]) = make_uint2(lo, hi);  // 8B aligned
    }
#pragma unroll
    for (int p = 0; p < 2; p++)
      *(uint4*)(&Ylds[(m0 + p*32) * 72 + cY * 8]) = ybuf[p];
    __syncthreads();
    if (it + 1 < NIT) gload(it + 1);   // prefetch overlaps MFMA below

#pragma unroll
    for (int ks = 0; ks < 2; ks++){
      short8 af[4];
#pragma unroll
      for (int mt = 0; mt < 4; mt++)    // A-frag: yT[m=16mt+nn][k = ks*32+q*8 ..+7]
        af[mt] = *(const short8*)(&Ylds[(mt*16 + nn) * 72 + ks*32 + q*8]);
#pragma unroll
      for (int nt = 0; nt < 2; nt++){
        const int col = wave * 32 + nt * 16 + nn;
        // B-frag: A[k = ks*32+q*8+jj][col]; swizzle key (k>>3)&3 == q for jj<8
        const short* bp = &Alds[(ks*32 + q*8) * 128
                                + (((col >> 3) ^ (2*q)) * 8) + (col & 7)];
        short8 bf;
#pragma unroll
        for (int jj = 0; jj < 8; jj++) bf[jj] = bp[jj * 128];  // imm-offset u16s
#pragma unroll
        for (int mt = 0; mt < 4; mt++)
          acc[mt][nt] = __builtin_amdgcn_mfma_f32_16x16x32_bf16(af[mt], bf, acc[mt][nt], 0, 0, 0);
      }
    }
  }

  // epilogue: C/D layout col=lane&15, row=q*4+reg
#pragma unroll
  for (int mt = 0; mt < 4; mt++)
#pragma unroll
    for (int nt = 0; nt < 2; nt++)
#pragma unroll
      for (int v = 0; v < 4; v++){
        const int d   = mt * 16 + q * 4 + v;
        const int col = j0 + wave * 32 + nt * 16 + nn;
        atomicAdd(accT + d * NN + col, acc[mt][nt][v]);
      }
}

// ---------------------------------------------------------------------------
// Kernel 3: out[j][d] = accT[d][j]  (FLOAT32 out) via LDS transpose
// ---------------------------------------------------------------------------
__global__ __launch_bounds__(256) void k_out(
    const float* __restrict__ accT, float* __restrict__ out)
{
  __shared__ float t[64][65];      // +1 pad: transposed reads are 2-way (free)
  const int tid = threadIdx.x;
  const int jb  = blockIdx.x * 64;

#pragma unroll
  for (int rep = 0; rep < 16; rep++){
    const int d = rep * 4 + (tid >> 6);
    const int j = tid & 63;
    t[d][j] = accT[d * NN + jb + j];          // coalesced 256B rows
  }
  __syncthreads();
#pragma unroll
  for (int rep = 0; rep < 16; rep++){
    const int j = rep * 4 + (tid >> 6);
    const int d = tid & 63;
    out[(jb + j) * DD + d] = t[d][j];         // coalesced 256B rows
  }
}

extern "C" void kernel_launch(void* const* d_in, const int* in_sizes, int n_in,
                              void* d_out, int out_size, void* d_ws, size_t ws_size,
                              hipStream_t stream) {
  const float* x     = (const float*)d_in[0];
  const float* r     = (const float*)d_in[1];
  const float* A     = (const float*)d_in[2];
  const float* Wobj  = (const float*)d_in[3];
  const float* bobj  = (const float*)d_in[4];
  const float* Wnobj = (const float*)d_in[5];
  const float* bnobj = (const float*)d_in[6];
  const float* Wrel  = (const float*)d_in[7];
  const float* brel  = (const float*)d_in[8];
  const float* Wskip = (const float*)d_in[9];
  const float* bskip = (const float*)d_in[10];
  // d_in[11] (Wa_w) and d_in[12] (Wa_b) are provably unused: softmax rows sum to 1.

  float* accT        = (float*)d_ws;                                        // 2 MB
  unsigned short* yT = (unsigned short*)((char*)d_ws + (size_t)DD*NN*4);    // 1 MB

  k_proj<<<dim3(32, 8), 256, 0, stream>>>(x, r, Wobj, bobj, Wnobj, bnobj,
                                          Wrel, brel, Wskip, bskip, accT, yT);
  k_spmm<<<dim3(NN / BN, KSPLIT), 256, 0, stream>>>(A, yT, accT);
  k_out<<<NN / 64, 256, 0, stream>>>(accT, (float*)d_out);
}